// Round 5
// baseline (185.790 us; speedup 1.0000x reference)
//
#include <hip/hip_runtime.h>

// GSKAN layer: out[b,q] = sum_p prelu(x[b,p] + eps[q]) * Lam[p,q]
// prelu(s) = c1*s + c2*|s|,  c1 = (1+a)/2, c2 = (1-a)/2  (|s| = free VOP3 modifier)
//
// Block: 256 threads, output tile 64(b) x 128(q); thread tile 4(b) x 8(q)
// (q split as two halves qg*4 and 64+qg*4 so ls reads are 2-way-free on banks).
// Per 4-p step per wave: 384 VALU instr (768 SIMD-cyc) vs 12 ds_read_b128
// (144 LDS-pipe cyc) -> VALU-bound, LDS pipe <= 75%.
// __launch_bounds__(256,4): VGPR <= 128 -> 4 waves/SIMD for latency hiding.
// p split across blockIdx.z into partials; deterministic combine after.

#define PCHUNK 32
#define XS_STRIDE 36   // 32 + 4 pad: row stride 144B -> consecutive rows 2-way alias only

__global__ __launch_bounds__(256, 4) void gskan_partial_kernel(
    const float* __restrict__ X,     // [B][n_in]
    const float* __restrict__ Lam,   // [n_in][n_out]
    const float* __restrict__ Eps,   // [n_out]
    const float* __restrict__ Aw,    // [1]
    float* __restrict__ Part,        // [nsplit][B][n_out]
    int B, int n_in, int n_out, int p_per_split)
{
    __shared__ float xs[64 * XS_STRIDE];   // 9.2 KB
    __shared__ float ls[PCHUNK * 128];     // 16 KB   [p][q], q contiguous

    const int tid = threadIdx.x;
    const int qg  = tid & 15;   // 16 q-groups; thread owns q = qg*4..+3 and 64+qg*4..+3
    const int bl  = tid >> 4;   // 16 b-groups of 4 rows

    const int q0 = blockIdx.x * 128;
    const int b0 = blockIdx.y * 64;
    const int p_begin = blockIdx.z * p_per_split;
    int p_end = p_begin + p_per_split;
    if (p_end > n_in) p_end = n_in;

    const float a  = Aw[0];
    const float c1 = 0.5f * (1.0f + a);
    const float c2 = 0.5f * (1.0f - a);

    float ee[8];
    {
        float4 eA = *reinterpret_cast<const float4*>(Eps + q0 + qg * 4);
        float4 eB = *reinterpret_cast<const float4*>(Eps + q0 + 64 + qg * 4);
        ee[0] = eA.x; ee[1] = eA.y; ee[2] = eA.z; ee[3] = eA.w;
        ee[4] = eB.x; ee[5] = eB.y; ee[6] = eB.z; ee[7] = eB.w;
    }

    float acc1[4][8] = {};
    float acc2[4][8] = {};

    for (int pc = p_begin; pc < p_end; pc += PCHUNK) {
        // stage X: 64 rows x 32 p = 2048 floats, 2 float4/thread; 128B/row-octet coalesced
        #pragma unroll
        for (int r = 0; r < 2; ++r) {
            int slot = r * 256 + tid;        // 0..511
            int row  = slot >> 3;            // 0..63
            int pg   = slot & 7;             // 0..7
            float4 v = *reinterpret_cast<const float4*>(
                X + (size_t)(b0 + row) * n_in + pc + pg * 4);
            *reinterpret_cast<float4*>(&xs[row * XS_STRIDE + pg * 4]) = v;
        }
        // stage Lam: 32 p x 128 q = 4096 floats, 4 float4/thread; 512B/row coalesced
        #pragma unroll
        for (int r = 0; r < 4; ++r) {
            int slot = r * 256 + tid;        // 0..1023
            int row  = slot >> 5;            // 0..31
            int c4   = slot & 31;
            float4 v = *reinterpret_cast<const float4*>(
                Lam + (size_t)(pc + row) * n_out + q0 + c4 * 4);
            *reinterpret_cast<float4*>(&ls[row * 128 + c4 * 4]) = v;
        }
        __syncthreads();

        #pragma unroll 2
        for (int p = 0; p < PCHUNK; p += 4) {
            float4 xv[4];
            #pragma unroll
            for (int i = 0; i < 4; ++i)
                xv[i] = *reinterpret_cast<const float4*>(&xs[(bl * 4 + i) * XS_STRIDE + p]);

            #pragma unroll
            for (int pp = 0; pp < 4; ++pp) {
                float4 lA = *reinterpret_cast<const float4*>(&ls[(p + pp) * 128 + qg * 4]);
                float4 lB = *reinterpret_cast<const float4*>(&ls[(p + pp) * 128 + 64 + qg * 4]);
                const float la[4] = {lA.x, lA.y, lA.z, lA.w};
                const float lb[4] = {lB.x, lB.y, lB.z, lB.w};
                #pragma unroll
                for (int i = 0; i < 4; ++i) {
                    const float xe = (pp == 0) ? xv[i].x :
                                     (pp == 1) ? xv[i].y :
                                     (pp == 2) ? xv[i].z : xv[i].w;
                    #pragma unroll
                    for (int j = 0; j < 4; ++j) {
                        const float sA = xe + ee[j];
                        acc1[i][j]     = fmaf(sA,        la[j], acc1[i][j]);
                        acc2[i][j]     = fmaf(fabsf(sA), la[j], acc2[i][j]);
                        const float sB = xe + ee[4 + j];
                        acc1[i][4 + j] = fmaf(sB,        lb[j], acc1[i][4 + j]);
                        acc2[i][4 + j] = fmaf(fabsf(sB), lb[j], acc2[i][4 + j]);
                    }
                }
            }
        }
        __syncthreads();  // WAR: next chunk overwrites LDS
    }

    float* P = Part + (size_t)blockIdx.z * B * n_out;
    #pragma unroll
    for (int i = 0; i < 4; ++i) {
        const int b = b0 + bl * 4 + i;
        float4 oA, oB;
        oA.x = c1 * acc1[i][0] + c2 * acc2[i][0];
        oA.y = c1 * acc1[i][1] + c2 * acc2[i][1];
        oA.z = c1 * acc1[i][2] + c2 * acc2[i][2];
        oA.w = c1 * acc1[i][3] + c2 * acc2[i][3];
        oB.x = c1 * acc1[i][4] + c2 * acc2[i][4];
        oB.y = c1 * acc1[i][5] + c2 * acc2[i][5];
        oB.z = c1 * acc1[i][6] + c2 * acc2[i][6];
        oB.w = c1 * acc1[i][7] + c2 * acc2[i][7];
        *reinterpret_cast<float4*>(P + (size_t)b * n_out + q0 + qg * 4) = oA;
        *reinterpret_cast<float4*>(P + (size_t)b * n_out + q0 + 64 + qg * 4) = oB;
    }
}

__global__ __launch_bounds__(256) void gskan_combine_kernel(
    const float* __restrict__ Part, float* __restrict__ Y, int n, int nsplit)
{
    int i = (blockIdx.x * 256 + threadIdx.x) * 4;
    if (i >= n) return;
    float4 acc = *reinterpret_cast<const float4*>(Part + i);
    for (int s = 1; s < nsplit; ++s) {
        float4 v = *reinterpret_cast<const float4*>(Part + (size_t)s * n + i);
        acc.x += v.x; acc.y += v.y; acc.z += v.z; acc.w += v.w;
    }
    *reinterpret_cast<float4*>(Y + i) = acc;
}

extern "C" void kernel_launch(void* const* d_in, const int* in_sizes, int n_in_args,
                              void* d_out, int out_size, void* d_ws, size_t ws_size,
                              hipStream_t stream)
{
    (void)n_in_args; (void)out_size;

    const float* x = (const float*)d_in[0];

    struct LayerP { const float *Lam, *Eps, *Aw; int n_in, n_out; };
    LayerP layers[4];
    for (int i = 0; i < 4; ++i) {
        layers[i].Lam   = (const float*)d_in[1 + 3 * i];
        layers[i].Eps   = (const float*)d_in[2 + 3 * i];
        layers[i].Aw    = (const float*)d_in[3 + 3 * i];
        layers[i].n_out = in_sizes[2 + 3 * i];
        layers[i].n_in  = in_sizes[1 + 3 * i] / layers[i].n_out;
    }
    const int B = in_sizes[0] / layers[0].n_in;

    // ws layout: [Part: 16MB][yA: 2MB][yB: 2MB]
    char* ws = (char*)d_ws;
    float* Part = (float*)ws;
    float* yA   = (float*)(ws + (size_t)(16u << 20));
    float* yB   = (float*)(ws + (size_t)(18u << 20));
    const bool have_ws = ws_size >= (size_t)(20u << 20);

    const float* cur = x;
    for (int i = 0; i < 4; ++i) {
        const LayerP& ly = layers[i];
        const int nq = ly.n_out / 128;
        const int nb = B / 64;

        int nsplit = 1;
        if (have_ws) {
            nsplit = 512 / (nq * nb);               // target ~512 blocks (2/CU)
            if (nsplit < 1) nsplit = 1;
            int max_split = ly.n_in / PCHUNK;
            if (nsplit > max_split) nsplit = max_split;
        }
        int p_per = ((ly.n_in + nsplit * PCHUNK - 1) / (nsplit * PCHUNK)) * PCHUNK;
        nsplit = (ly.n_in + p_per - 1) / p_per;

        float* Y = (i == 3) ? (float*)d_out : ((i % 2 == 0) ? yA : yB);
        float* dst = (nsplit == 1) ? Y : Part;

        dim3 grid(nq, nb, nsplit), block(256);
        hipLaunchKernelGGL(gskan_partial_kernel, grid, block, 0, stream,
                           cur, ly.Lam, ly.Eps, ly.Aw, dst,
                           B, ly.n_in, ly.n_out, p_per);

        if (nsplit > 1) {
            const int n = B * ly.n_out;
            dim3 cg((n / 4 + 255) / 256), cb(256);
            hipLaunchKernelGGL(gskan_combine_kernel, cg, cb, 0, stream, Part, Y, n, nsplit);
        }
        cur = Y;
    }
}

// Round 6
// 117.433 us; speedup vs baseline: 1.5821x; 1.5821x over previous
//
#include <hip/hip_runtime.h>

// GSKAN layer: out[b,q] = sum_p prelu(x[b,p] + eps[q]) * Lam[p,q]
// prelu(s) = c1*s + c2*|s|,  c1 = (1+a)/2, c2 = (1-a)/2  (|s| = free VOP3 modifier)
//
// Block: 256 threads, output tile 64(b) x 64(q); thread tile 4(b) x 4(q).
// 32 accumulators -> natural VGPR ~100 (no launch-bounds cap: R5 showed a
// forced cap spills 42MB/dispatch of scratch). Occupancy comes from the grid:
// nsplit chosen so every layer launches ~1024 blocks = 4 blocks/CU = 16 waves/CU.
// xs stride 36 floats -> the 4 rows a thread reads sit on bank quads +0/+4/+8/+12.

#define PCHUNK 32
#define XS_STRIDE 36

__global__ __launch_bounds__(256) void gskan_partial_kernel(
    const float* __restrict__ X,     // [B][n_in]
    const float* __restrict__ Lam,   // [n_in][n_out]
    const float* __restrict__ Eps,   // [n_out]
    const float* __restrict__ Aw,    // [1]
    float* __restrict__ Part,        // [nsplit][B][n_out]
    int B, int n_in, int n_out, int p_per_split)
{
    __shared__ float xs[64 * XS_STRIDE];   // 9.2 KB
    __shared__ float ls[PCHUNK * 64];      // 8 KB  [p][q]

    const int tid = threadIdx.x;
    const int qg  = tid & 15;   // q-group: thread owns q = q0 + qg*4 .. +3
    const int bl  = tid >> 4;   // b-group: rows b0 + bl*4 .. +3

    const int q0 = blockIdx.x * 64;
    const int b0 = blockIdx.y * 64;
    const int p_begin = blockIdx.z * p_per_split;
    int p_end = p_begin + p_per_split;
    if (p_end > n_in) p_end = n_in;

    const float a  = Aw[0];
    const float c1 = 0.5f * (1.0f + a);
    const float c2 = 0.5f * (1.0f - a);

    const float4 ev = *reinterpret_cast<const float4*>(Eps + q0 + qg * 4);
    const float ee[4] = {ev.x, ev.y, ev.z, ev.w};

    float acc1[4][4] = {};
    float acc2[4][4] = {};

    for (int pc = p_begin; pc < p_end; pc += PCHUNK) {
        // stage X: 64 rows x 32 p = 512 float4, 2 per thread; 8 rows/wave, 128B/row
        #pragma unroll
        for (int r = 0; r < 2; ++r) {
            int slot = r * 256 + tid;        // 0..511
            int row  = slot >> 3;            // 0..63
            int pg   = slot & 7;             // 0..7
            float4 v = *reinterpret_cast<const float4*>(
                X + (size_t)(b0 + row) * n_in + pc + pg * 4);
            *reinterpret_cast<float4*>(&xs[row * XS_STRIDE + pg * 4]) = v;
        }
        // stage Lam: 32 p x 64 q = 512 float4, 2 per thread; 256B/row
        #pragma unroll
        for (int r = 0; r < 2; ++r) {
            int slot = r * 256 + tid;        // 0..511
            int row  = slot >> 4;            // 0..31
            int c4   = slot & 15;
            float4 v = *reinterpret_cast<const float4*>(
                Lam + (size_t)(pc + row) * n_out + q0 + c4 * 4);
            *reinterpret_cast<float4*>(&ls[row * 64 + c4 * 4]) = v;
        }
        __syncthreads();

        #pragma unroll
        for (int p = 0; p < PCHUNK; p += 4) {
            float4 xv[4];
            #pragma unroll
            for (int i = 0; i < 4; ++i)
                xv[i] = *reinterpret_cast<const float4*>(&xs[(bl * 4 + i) * XS_STRIDE + p]);

            #pragma unroll
            for (int pp = 0; pp < 4; ++pp) {
                float4 lv = *reinterpret_cast<const float4*>(&ls[(p + pp) * 64 + qg * 4]);
                const float le[4] = {lv.x, lv.y, lv.z, lv.w};
                #pragma unroll
                for (int i = 0; i < 4; ++i) {
                    const float xe = (pp == 0) ? xv[i].x :
                                     (pp == 1) ? xv[i].y :
                                     (pp == 2) ? xv[i].z : xv[i].w;
                    #pragma unroll
                    for (int j = 0; j < 4; ++j) {
                        const float s = xe + ee[j];
                        acc1[i][j] = fmaf(s,        le[j], acc1[i][j]);
                        acc2[i][j] = fmaf(fabsf(s), le[j], acc2[i][j]);
                    }
                }
            }
        }
        __syncthreads();  // WAR: next chunk overwrites LDS
    }

    float* P = Part + (size_t)blockIdx.z * B * n_out;
    #pragma unroll
    for (int i = 0; i < 4; ++i) {
        const int b = b0 + bl * 4 + i;
        float4 o;
        o.x = c1 * acc1[i][0] + c2 * acc2[i][0];
        o.y = c1 * acc1[i][1] + c2 * acc2[i][1];
        o.z = c1 * acc1[i][2] + c2 * acc2[i][2];
        o.w = c1 * acc1[i][3] + c2 * acc2[i][3];
        *reinterpret_cast<float4*>(P + (size_t)b * n_out + q0 + qg * 4) = o;
    }
}

__global__ __launch_bounds__(256) void gskan_combine_kernel(
    const float* __restrict__ Part, float* __restrict__ Y, int n, int nsplit)
{
    int i = (blockIdx.x * 256 + threadIdx.x) * 4;
    if (i >= n) return;
    float4 acc = *reinterpret_cast<const float4*>(Part + i);
    for (int s = 1; s < nsplit; ++s) {
        float4 v = *reinterpret_cast<const float4*>(Part + (size_t)s * n + i);
        acc.x += v.x; acc.y += v.y; acc.z += v.z; acc.w += v.w;
    }
    *reinterpret_cast<float4*>(Y + i) = acc;
}

extern "C" void kernel_launch(void* const* d_in, const int* in_sizes, int n_in_args,
                              void* d_out, int out_size, void* d_ws, size_t ws_size,
                              hipStream_t stream)
{
    (void)n_in_args; (void)out_size;

    const float* x = (const float*)d_in[0];

    struct LayerP { const float *Lam, *Eps, *Aw; int n_in, n_out; };
    LayerP layers[4];
    for (int i = 0; i < 4; ++i) {
        layers[i].Lam   = (const float*)d_in[1 + 3 * i];
        layers[i].Eps   = (const float*)d_in[2 + 3 * i];
        layers[i].Aw    = (const float*)d_in[3 + 3 * i];
        layers[i].n_out = in_sizes[2 + 3 * i];
        layers[i].n_in  = in_sizes[1 + 3 * i] / layers[i].n_out;
    }
    const int B = in_sizes[0] / layers[0].n_in;

    // ws layout: [Part: 16MB][yA: 2MB][yB: 2MB]
    char* ws = (char*)d_ws;
    float* Part = (float*)ws;
    float* yA   = (float*)(ws + (size_t)(16u << 20));
    float* yB   = (float*)(ws + (size_t)(18u << 20));
    const bool have_ws = ws_size >= (size_t)(20u << 20);

    const float* cur = x;
    for (int i = 0; i < 4; ++i) {
        const LayerP& ly = layers[i];
        const int nq = ly.n_out / 64;
        const int nb = B / 64;

        int nsplit = 1;
        if (have_ws) {
            nsplit = 1024 / (nq * nb);              // target ~1024 blocks = 4/CU
            if (nsplit < 1) nsplit = 1;
            int max_split = ly.n_in / PCHUNK;
            if (nsplit > max_split) nsplit = max_split;
        }
        int p_per = ((ly.n_in + nsplit * PCHUNK - 1) / (nsplit * PCHUNK)) * PCHUNK;
        nsplit = (ly.n_in + p_per - 1) / p_per;

        // Part capacity guard: nsplit * B * n_out floats must fit 16MB
        while ((size_t)nsplit * B * ly.n_out * 4 > ((size_t)16u << 20)) nsplit--;
        if (nsplit < 1) nsplit = 1;
        p_per = ((ly.n_in + nsplit * PCHUNK - 1) / (nsplit * PCHUNK)) * PCHUNK;
        nsplit = (ly.n_in + p_per - 1) / p_per;

        float* Y = (i == 3) ? (float*)d_out : ((i % 2 == 0) ? yA : yB);
        float* dst = (nsplit == 1) ? Y : Part;

        dim3 grid(nq, nb, nsplit), block(256);
        hipLaunchKernelGGL(gskan_partial_kernel, grid, block, 0, stream,
                           cur, ly.Lam, ly.Eps, ly.Aw, dst,
                           B, ly.n_in, ly.n_out, p_per);

        if (nsplit > 1) {
            const int n = B * ly.n_out;
            dim3 cg((n / 4 + 255) / 256), cb(256);
            hipLaunchKernelGGL(gskan_combine_kernel, cg, cb, 0, stream, Part, Y, n, nsplit);
        }
        cur = Y;
    }
}